// Round 8
// baseline (256.939 us; speedup 1.0000x reference)
//
#include <hip/hip_runtime.h>
#include <hip/hip_bf16.h>
#include <math.h>

// Problem constants: N=2, D=384, 2U=256, nH=8, hd=48, nL=4, nP=4
#define DM   384
#define U2   256
#define HD   48

typedef __attribute__((ext_vector_type(8))) short short8;   // 8 bf16 = 4 VGPR
typedef __attribute__((ext_vector_type(4))) float floatx4;  // MFMA acc

static __device__ __forceinline__ unsigned short f2bfbits(float f) {
    __hip_bfloat16 h = __float2bfloat16(f);
    return *reinterpret_cast<unsigned short*>(&h);
}
static __device__ __forceinline__ unsigned pack2(float x, float y) {
    return (unsigned)f2bfbits(x) | ((unsigned)f2bfbits(y) << 16);
}
static __device__ __forceinline__ float bflo(unsigned u) { return __uint_as_float(u << 16); }
static __device__ __forceinline__ float bfhi(unsigned u) { return __uint_as_float(u & 0xffff0000u); }

// =====================================================================
// Multi-segment MFMA GEMM, self-contained (no prep kernel):
//   - A: fp32 (aty=0, converted during staging) or bf16 (aty=1)
//   - B: original fp32 (K x N) weights, transposed in-LDS during staging
//   - 128x128 tile, BK=32, unpadded 64B LDS rows + XOR chunk swizzle
//     (phys 16B chunk p of row r holds logical chunk p ^ ((r>>1)&3))
// omode: 0 = f32 out; 1 = bf16 out; 2/3 = bf16 scatter into combined
// value layout (top/bot): idx = row*768 + (col/48)*96 + (omode==3)*48 + col%48
// =====================================================================
struct Seg {
    const void* A; int lda; int aty;     // aty: 0 = fp32, 1 = bf16
    const float* W; int ldw;             // (K x N) row-major fp32
    const float* bias; void* C; int ldc; int K; int omode;
};
struct SegParams { Seg seg[5]; int ystart[5]; int nseg; };

__global__ __launch_bounds__(256) void gemm_seg_kernel(SegParams p) {
    __shared__ __hip_bfloat16 As[128 * 32];
    __shared__ __hip_bfloat16 Bs[128 * 32];

    const int yb = blockIdx.y;
    int s = 0;
#pragma unroll
    for (int i = 1; i < 5; ++i) if (i < p.nseg && yb >= p.ystart[i]) s = i;
    Seg sg;
    switch (s) {
        case 0: sg = p.seg[0]; break;
        case 1: sg = p.seg[1]; break;
        case 2: sg = p.seg[2]; break;
        case 3: sg = p.seg[3]; break;
        default: sg = p.seg[4]; break;
    }
    const int by = yb - p.ystart[s];

    const int t    = threadIdx.x;
    const int bm   = blockIdx.x * 128;
    const int bn   = by * 128;
    const int w    = t >> 6, lane = t & 63;
    const int wm   = (w >> 1) * 64, wn = (w & 1) * 64;
    const int quad = lane >> 4, lm = lane & 15;

    // A staging map: thread -> (row = t>>1, half = t&1 -> k-sub 16)
    const int arow = t >> 1, ahalf = t & 1;
    const int ac0 = (ahalf * 2)     ^ ((arow >> 1) & 3);
    const int ac1 = (ahalf * 2 + 1) ^ ((arow >> 1) & 3);
    // B staging map: thread -> (n = t&127, kh = t>>7 -> k-sub 16)
    const int bn_ = t & 127, bkh = t >> 7;
    const int bc0 = (bkh * 2)     ^ ((bn_ >> 1) & 3);
    const int bc1 = (bkh * 2 + 1) ^ ((bn_ >> 1) & 3);

    floatx4 acc[4][4] = {};

    for (int k0 = 0; k0 < sg.K; k0 += 32) {
        // ---- stage A ----
        if (sg.aty) {
            const __hip_bfloat16* src = (const __hip_bfloat16*)sg.A +
                (size_t)(bm + arow) * sg.lda + k0 + ahalf * 16;
            *(short8*)&As[arow * 32 + ac0 * 8] = *(const short8*)src;
            *(short8*)&As[arow * 32 + ac1 * 8] = *(const short8*)(src + 8);
        } else {
            const float* src = (const float*)sg.A +
                (size_t)(bm + arow) * sg.lda + k0 + ahalf * 16;
            const float4 f0 = *(const float4*)(src + 0);
            const float4 f1 = *(const float4*)(src + 4);
            const float4 f2 = *(const float4*)(src + 8);
            const float4 f3 = *(const float4*)(src + 12);
            uint4 lo, hi;
            lo.x = pack2(f0.x, f0.y); lo.y = pack2(f0.z, f0.w);
            lo.z = pack2(f1.x, f1.y); lo.w = pack2(f1.z, f1.w);
            hi.x = pack2(f2.x, f2.y); hi.y = pack2(f2.z, f2.w);
            hi.z = pack2(f3.x, f3.y); hi.w = pack2(f3.z, f3.w);
            *(uint4*)&As[arow * 32 + ac0 * 8] = lo;
            *(uint4*)&As[arow * 32 + ac1 * 8] = hi;
        }
        // ---- stage B: transpose fp32 (K x N) slice -> bf16 (n x k) ----
        {
            const float* wsrc = sg.W + (size_t)(k0 + bkh * 16) * sg.ldw + bn + bn_;
            float v[16];
#pragma unroll
            for (int i = 0; i < 16; ++i) v[i] = wsrc[(size_t)i * sg.ldw];
            uint4 lo, hi;
            lo.x = pack2(v[0], v[1]);  lo.y = pack2(v[2], v[3]);
            lo.z = pack2(v[4], v[5]);  lo.w = pack2(v[6], v[7]);
            hi.x = pack2(v[8], v[9]);  hi.y = pack2(v[10], v[11]);
            hi.z = pack2(v[12], v[13]); hi.w = pack2(v[14], v[15]);
            *(uint4*)&Bs[bn_ * 32 + bc0 * 8] = lo;
            *(uint4*)&Bs[bn_ * 32 + bc1 * 8] = hi;
        }
        __syncthreads();

        short8 af[4], bf[4];
#pragma unroll
        for (int i = 0; i < 4; ++i) {
            const int row = wm + i * 16 + lm;
            af[i] = *(const short8*)&As[row * 32 + ((quad ^ ((row >> 1) & 3)) * 8)];
        }
#pragma unroll
        for (int j = 0; j < 4; ++j) {
            const int row = wn + j * 16 + lm;
            bf[j] = *(const short8*)&Bs[row * 32 + ((quad ^ ((row >> 1) & 3)) * 8)];
        }
#pragma unroll
        for (int i = 0; i < 4; ++i)
#pragma unroll
            for (int j = 0; j < 4; ++j)
                acc[i][j] = __builtin_amdgcn_mfma_f32_16x16x32_bf16(
                    af[i], bf[j], acc[i][j], 0, 0, 0);
        __syncthreads();
    }

#pragma unroll
    for (int i = 0; i < 4; ++i)
#pragma unroll
        for (int reg = 0; reg < 4; ++reg) {
            const int row = bm + wm + i * 16 + quad * 4 + reg;
#pragma unroll
            for (int j = 0; j < 4; ++j) {
                const int col = bn + wn + j * 16 + lm;
                const float v = acc[i][j][reg] + sg.bias[col];
                if (sg.omode == 0) {
                    ((float*)sg.C)[(size_t)row * sg.ldc + col] = v;
                } else if (sg.omode == 1) {
                    ((__hip_bfloat16*)sg.C)[(size_t)row * sg.ldc + col] = __float2bfloat16(v);
                } else {
                    const int h = col / 48;
                    const size_t idx = (size_t)row * 768 + h * 96 +
                                       ((sg.omode == 3) ? 48 : 0) + (col - h * 48);
                    ((__hip_bfloat16*)sg.C)[idx] = __float2bfloat16(v);
                }
            }
        }
}

// =====================================================================
// Fused sampler, 2 queries per 192-thread block (round-5 best config).
// Phase 3: 96 threads/query; (br,h) group of 6 threads; uint4 gathers from
// combined value layout (point row 1536B = [h][br][48ch]); 12 consecutive
// lanes read one contiguous 192B slab (exactly 3 cache lines).
// =====================================================================
#define SPP 524

__global__ __launch_bounds__(192) void sampler_kernel(
    const float* __restrict__ off_buf,    // (M, 256) fp32
    const float* __restrict__ logit_top,  // (M, 128)
    const float* __restrict__ logit_bot,  // (M, 128)
    const float* __restrict__ ref_pts,    // (M, 4, 2)
    const int*   __restrict__ ss,         // (4,2) [H,W]
    const int*   __restrict__ lsi,        // (4,)
    const __hip_bfloat16* __restrict__ vcomb,  // (Mv, 768) combined
    __hip_bfloat16* __restrict__ core_top,     // (M, 384) bf16
    __hip_bfloat16* __restrict__ core_bot,     // (M, 384) bf16
    int Lq, int LenIn)
{
    __shared__ float    sA[4][128];   // [q*2+br][e]
    __shared__ unsigned sP[4][SPP];   // packed (bf16 w)<<16 | point

    const int bid = blockIdx.x;
    const int Q0  = bid * 2;
    const int t   = threadIdx.x;

    float gw[2][4];
    int   gp[2][4];
#pragma unroll
    for (int slot = 0; slot < 2; ++slot) {
        const bool active = slot ? (t >= 64) : (t < 128);
        if (!active) continue;
        const int qL = slot;
        const int e  = slot ? (t - 64) : t;
        const int gq = Q0 + qL;
        const int n  = gq / Lq;
        const int l  = (e >> 2) & 3;
        const float2 offv = *(const float2*)&off_buf[(size_t)gq * 256 + 2 * e];
        const float rx = ref_pts[(size_t)(gq * 4 + l) * 2 + 0];
        const float ry = ref_pts[(size_t)(gq * 4 + l) * 2 + 1];
        const int H = ss[2 * l], W = ss[2 * l + 1];
        const int start = lsi[l];

        const float x = (rx + offv.x / (float)W) * (float)W - 0.5f;
        const float y = (ry + offv.y / (float)H) * (float)H - 0.5f;
        const float x0f = floorf(x), y0f = floorf(y);
        const float lx = x - x0f, ly = y - y0f;
        const int ix0 = (int)x0f, iy0 = (int)y0f;
        const int ix1 = ix0 + 1,  iy1 = iy0 + 1;

        const float vx0 = (ix0 >= 0 && ix0 < W) ? 1.f : 0.f;
        const float vx1 = (ix1 >= 0 && ix1 < W) ? 1.f : 0.f;
        const float vy0 = (iy0 >= 0 && iy0 < H) ? 1.f : 0.f;
        const float vy1 = (iy1 >= 0 && iy1 < H) ? 1.f : 0.f;
        const int cx0 = min(max(ix0, 0), W - 1);
        const int cx1 = min(max(ix1, 0), W - 1);
        const int cy0 = min(max(iy0, 0), H - 1);
        const int cy1 = min(max(iy1, 0), H - 1);
        const int base = n * LenIn + start;

        gp[slot][0] = base + cy0 * W + cx0;
        gp[slot][1] = base + cy0 * W + cx1;
        gp[slot][2] = base + cy1 * W + cx0;
        gp[slot][3] = base + cy1 * W + cx1;
        gw[slot][0] = (1.f - lx) * (1.f - ly) * vx0 * vy0;
        gw[slot][1] = lx * (1.f - ly) * vx1 * vy0;
        gw[slot][2] = (1.f - lx) * ly * vx0 * vy1;
        gw[slot][3] = lx * ly * vx1 * vy1;
    }

    // ---- softmax: t<32 -> (q = t>>4, br = (t>>3)&1, h = t&7) ----
    if (t < 32) {
        const int q  = t >> 4;
        const int br = (t >> 3) & 1;
        const int h  = t & 7;
        const float* L = (br ? logit_bot : logit_top) + (size_t)(Q0 + q) * 128 + h * 16;
        float lg[16];
        *(float4*)&lg[0]  = *(const float4*)&L[0];
        *(float4*)&lg[4]  = *(const float4*)&L[4];
        *(float4*)&lg[8]  = *(const float4*)&L[8];
        *(float4*)&lg[12] = *(const float4*)&L[12];
        float m = -1e30f;
#pragma unroll
        for (int j = 0; j < 16; ++j) m = fmaxf(m, lg[j]);
        float ex[16], sum = 0.f;
#pragma unroll
        for (int j = 0; j < 16; ++j) { ex[j] = expf(lg[j] - m); sum += ex[j]; }
        const float inv = 1.f / sum;
#pragma unroll
        for (int j = 0; j < 16; ++j) sA[q * 2 + br][h * 16 + j] = ex[j] * inv;
    }
    __syncthreads();

    // ---- pack premultiplied weights + point indices ----
#pragma unroll
    for (int slot = 0; slot < 2; ++slot) {
        const bool active = slot ? (t >= 64) : (t < 128);
        if (!active) continue;
        const int e = slot ? (t - 64) : t;
        const int pidx = 4 * e + (e >> 4);
#pragma unroll
        for (int br = 0; br < 2; ++br) {
            const float a = sA[slot * 2 + br][e];
#pragma unroll
            for (int k = 0; k < 4; ++k) {
                sP[slot * 2 + br][pidx + k] =
                    ((unsigned)f2bfbits(gw[slot][k] * a) << 16) | (unsigned)gp[slot][k];
            }
        }
    }
    __syncthreads();

    // ---- phase 3: gathers ----
    const int q  = t / 96;
    const int r  = t - q * 96;
    const int g  = r / 6;
    const int m  = r - g * 6;
    const int br = g & 1;
    const int h  = g >> 1;

    const unsigned* P = sP[q * 2 + br];
    const char* vb = (const char*)vcomb + h * 192 + br * 96 + m * 16;

    float a0 = 0.f, a1 = 0.f, a2 = 0.f, a3 = 0.f;
    float a4 = 0.f, a5 = 0.f, a6 = 0.f, a7 = 0.f;
#pragma unroll 4
    for (int lp = 0; lp < 16; ++lp) {
        const int ib = 65 * h + 4 * lp;
#pragma unroll
        for (int k = 0; k < 4; ++k) {
            const unsigned u = P[ib + k];
            const float wv = __uint_as_float(u & 0xffff0000u);
            const unsigned pt = u & 0x3fffu;
            const uint4 v = *(const uint4*)(vb + pt * 1536u);
            a0 = fmaf(wv, bflo(v.x), a0);
            a1 = fmaf(wv, bfhi(v.x), a1);
            a2 = fmaf(wv, bflo(v.y), a2);
            a3 = fmaf(wv, bfhi(v.y), a3);
            a4 = fmaf(wv, bflo(v.z), a4);
            a5 = fmaf(wv, bfhi(v.z), a5);
            a6 = fmaf(wv, bflo(v.w), a6);
            a7 = fmaf(wv, bfhi(v.w), a7);
        }
    }
    uint4 o;
    o.x = pack2(a0, a1); o.y = pack2(a2, a3);
    o.z = pack2(a4, a5); o.w = pack2(a6, a7);
    __hip_bfloat16* dst = br ? core_bot : core_top;
    *(uint4*)&dst[(size_t)(Q0 + q) * DM + h * HD + m * 8] = o;
}

// =====================================================================
// Host launcher — 3 dispatches, no prep kernel.
// =====================================================================
extern "C" void kernel_launch(void* const* d_in, const int* in_sizes, int n_in,
                              void* d_out, int out_size, void* d_ws, size_t ws_size,
                              hipStream_t stream) {
    const float* query   = (const float*)d_in[0];
    const float* refpts  = (const float*)d_in[1];
    const float* flat    = (const float*)d_in[2];
    const int*   ss      = (const int*)d_in[3];
    const int*   lsi     = (const int*)d_in[4];
    const float* W_off   = (const float*)d_in[5];
    const float* b_off   = (const float*)d_in[6];
    const float* W_attn  = (const float*)d_in[7];
    const float* b_attn  = (const float*)d_in[8];
    const float* W_val   = (const float*)d_in[9];
    const float* b_val   = (const float*)d_in[10];
    const float* W_out   = (const float*)d_in[11];
    const float* b_out   = (const float*)d_in[12];
    const float* W_attn_zd = (const float*)d_in[13];
    const float* b_attn_zd = (const float*)d_in[14];
    const float* W_val_zd  = (const float*)d_in[15];
    const float* b_val_zd  = (const float*)d_in[16];
    const float* W_out_zd  = (const float*)d_in[17];
    const float* b_out_zd  = (const float*)d_in[18];

    const int Lq    = in_sizes[0] / (2 * DM);   // 5440
    const int LenIn = in_sizes[2] / (2 * DM);   // 5440
    const int M  = 2 * Lq;      // 10880
    const int Mv = 2 * LenIn;   // 10880

    float* out = (float*)d_out;

    // ---- workspace layout ----
    float* ws      = (float*)d_ws;
    float* off_buf = ws;                               // M*256 f32
    float* lt      = off_buf + (size_t)M * 256;        // M*128 f32
    float* lb      = lt + (size_t)M * 128;             // M*128 f32
    __hip_bfloat16* vcomb = (__hip_bfloat16*)(lb + (size_t)M * 128); // Mv*768
    __hip_bfloat16* ct    = vcomb + (size_t)Mv * 768;  // M*384
    __hip_bfloat16* cb    = ct + (size_t)M * 384;      // M*384

    const dim3 blk(256);
    const int mg = M / 128;   // 85

    // ---- MEGA-GEMM 1: off + logits + values(combined scatter), grid (85,10)
    {
        SegParams p;
        p.seg[0] = { query, DM, 0, W_off,     256, b_off,     off_buf, 256, 256, 0 }; // y0-1
        p.seg[1] = { query, DM, 0, W_attn,    128, b_attn,    lt,      128, 256, 0 }; // y2
        p.seg[2] = { query, DM, 0, W_attn_zd, 128, b_attn_zd, lb,      128, 384, 0 }; // y3
        p.seg[3] = { flat,  DM, 0, W_val,     384, b_val,     vcomb,   0,   256, 2 }; // y4-6
        p.seg[4] = { flat,  DM, 0, W_val_zd,  384, b_val_zd,  vcomb,   0,   384, 3 }; // y7-9
        p.ystart[0] = 0; p.ystart[1] = 2; p.ystart[2] = 3;
        p.ystart[3] = 4; p.ystart[4] = 7;
        p.nseg = 5;
        gemm_seg_kernel<<<dim3(mg, 10), blk, 0, stream>>>(p);
    }

    // ---- sampler: 2 queries per 192-thread block ----
    sampler_kernel<<<dim3(M / 2), dim3(192), 0, stream>>>(
        off_buf, lt, lb, refpts, ss, lsi, vcomb, ct, cb, Lq, LenIn);

    // ---- MEGA-GEMM 2: output projections, grid (85,3) ----
    {
        SegParams p;
        p.seg[0] = { ct, DM, 1, W_out,    256, b_out,    out,      DM, 384, 0 }; // y0-1
        p.seg[1] = { cb, DM, 1, W_out_zd, 128, b_out_zd, out + U2, DM, 384, 0 }; // y2
        p.ystart[0] = 0; p.ystart[1] = 2;
        p.nseg = 2;
        gemm_seg_kernel<<<dim3(mg, 3), blk, 0, stream>>>(p);
    }
}

// Round 9
// 255.881 us; speedup vs baseline: 1.0041x; 1.0041x over previous
//
#include <hip/hip_runtime.h>
#include <hip/hip_bf16.h>
#include <math.h>

// Problem constants: N=2, D=384, 2U=256, nH=8, hd=48, nL=4, nP=4
#define DM   384
#define U2   256
#define HD   48

typedef __attribute__((ext_vector_type(8))) short short8;   // 8 bf16 = 4 VGPR
typedef __attribute__((ext_vector_type(4))) float floatx4;  // MFMA acc

static __device__ __forceinline__ unsigned short f2bfbits(float f) {
    __hip_bfloat16 h = __float2bfloat16(f);
    return *reinterpret_cast<unsigned short*>(&h);
}
static __device__ __forceinline__ unsigned pack2(float x, float y) {
    return (unsigned)f2bfbits(x) | ((unsigned)f2bfbits(y) << 16);
}
static __device__ __forceinline__ float bflo(unsigned u) { return __uint_as_float(u << 16); }
static __device__ __forceinline__ float bfhi(unsigned u) { return __uint_as_float(u & 0xffff0000u); }

// =====================================================================
// Prep: 7 weight transposes (K x N fp32 -> N x K bf16). Tiny (~475K elems).
// =====================================================================
struct PrepParams {
    const float* wsrc[7]; __hip_bfloat16* wdst[7];
    int K[7], N[7], off[8];
    int total;
};
__global__ __launch_bounds__(256) void prep_kernel(PrepParams d) {
    const int iw = blockIdx.x * 256 + threadIdx.x;
    if (iw >= d.total) return;
    int s = 0;
#pragma unroll
    for (int i = 1; i < 7; ++i) if (iw >= d.off[i]) s = i;
    const int r = iw - d.off[s];
    const int k = r / d.N[s], n = r - k * d.N[s];
    d.wdst[s][(size_t)n * d.K[s] + k] = __float2bfloat16(d.wsrc[s][r]);
}

// =====================================================================
// Multi-segment MFMA GEMM (R5-proven padded-LDS staging):
//   - A: fp32 (aty=0, converted in VGPRs during staging) or bf16 (aty=1)
//   - B: pre-transposed bf16 (N x K), short8 vector loads
//   - 128x128 tile, BK=32, LDS rows padded to 40 elems (2-way max = free)
// omode: 0 = f32 out; 1 = bf16 out; 2/3 = bf16 scatter into combined
// value layout (top/bot): idx = row*768 + (col/48)*96 + (omode==3)*48 + col%48
// =====================================================================
struct Seg {
    const void* A; int lda; int aty;
    const __hip_bfloat16* Bt; int ldbt;
    const float* bias; void* C; int ldc; int K; int omode;
};
struct SegParams { Seg seg[5]; int ystart[5]; int nseg; };

__global__ __launch_bounds__(256) void gemm_seg_kernel(SegParams p) {
    __shared__ __hip_bfloat16 As[128 * 40];
    __shared__ __hip_bfloat16 Bs[128 * 40];

    const int yb = blockIdx.y;
    int s = 0;
#pragma unroll
    for (int i = 1; i < 5; ++i) if (i < p.nseg && yb >= p.ystart[i]) s = i;
    Seg sg;
    switch (s) {
        case 0: sg = p.seg[0]; break;
        case 1: sg = p.seg[1]; break;
        case 2: sg = p.seg[2]; break;
        case 3: sg = p.seg[3]; break;
        default: sg = p.seg[4]; break;
    }
    const int by = yb - p.ystart[s];

    const int t    = threadIdx.x;
    const int bm   = blockIdx.x * 128;
    const int bn   = by * 128;
    const int w    = t >> 6, lane = t & 63;
    const int wm   = (w >> 1) * 64, wn = (w & 1) * 64;
    const int quad = lane >> 4, lm = lane & 15;

    // staging map: chunk thread -> row r0(+64), k-chunk kc (8 elems)
    const int r0 = t >> 2, kc = (t & 3) * 8;

    floatx4 acc[4][4] = {};

    for (int k0 = 0; k0 < sg.K; k0 += 32) {
#pragma unroll
        for (int g = 0; g < 2; ++g) {
            const int row = r0 + 64 * g;
            // A
            if (sg.aty) {
                *(short8*)&As[row * 40 + kc] =
                    *(const short8*)((const __hip_bfloat16*)sg.A +
                        (size_t)(bm + row) * sg.lda + k0 + kc);
            } else {
                const float* src = (const float*)sg.A +
                    (size_t)(bm + row) * sg.lda + k0 + kc;
                const float4 f0 = *(const float4*)(src + 0);
                const float4 f1 = *(const float4*)(src + 4);
                uint4 u;
                u.x = pack2(f0.x, f0.y); u.y = pack2(f0.z, f0.w);
                u.z = pack2(f1.x, f1.y); u.w = pack2(f1.z, f1.w);
                *(uint4*)&As[row * 40 + kc] = u;
            }
            // B
            *(short8*)&Bs[row * 40 + kc] =
                *(const short8*)&sg.Bt[(size_t)(bn + row) * sg.ldbt + k0 + kc];
        }
        __syncthreads();

        short8 af[4], bf[4];
#pragma unroll
        for (int i = 0; i < 4; ++i)
            af[i] = *(const short8*)&As[(wm + i * 16 + lm) * 40 + quad * 8];
#pragma unroll
        for (int j = 0; j < 4; ++j)
            bf[j] = *(const short8*)&Bs[(wn + j * 16 + lm) * 40 + quad * 8];
#pragma unroll
        for (int i = 0; i < 4; ++i)
#pragma unroll
            for (int j = 0; j < 4; ++j)
                acc[i][j] = __builtin_amdgcn_mfma_f32_16x16x32_bf16(
                    af[i], bf[j], acc[i][j], 0, 0, 0);
        __syncthreads();
    }

#pragma unroll
    for (int i = 0; i < 4; ++i)
#pragma unroll
        for (int reg = 0; reg < 4; ++reg) {
            const int row = bm + wm + i * 16 + quad * 4 + reg;
#pragma unroll
            for (int j = 0; j < 4; ++j) {
                const int col = bn + wn + j * 16 + lm;
                const float v = acc[i][j][reg] + sg.bias[col];
                if (sg.omode == 0) {
                    ((float*)sg.C)[(size_t)row * sg.ldc + col] = v;
                } else if (sg.omode == 1) {
                    ((__hip_bfloat16*)sg.C)[(size_t)row * sg.ldc + col] = __float2bfloat16(v);
                } else {
                    const int h = col / 48;
                    const size_t idx = (size_t)row * 768 + h * 96 +
                                       ((sg.omode == 3) ? 48 : 0) + (col - h * 48);
                    ((__hip_bfloat16*)sg.C)[idx] = __float2bfloat16(v);
                }
            }
        }
}

// =====================================================================
// Fused sampler v9: ONE query per 192-thread block; the 16-point loop is
// split across two 96-thread halves (32 loads/thread, 2x loads in flight
// vs v5's 64); partials combined through LDS. ~8 KB LDS -> grid-bound
// occupancy (~10 blocks/CU resident).
// Phase 3 gather: (br,h) group of 6 threads; uint4 gathers from combined
// value layout (point row 1536B = [h][br][48ch]); 12 consecutive lanes
// read one contiguous 192B slab (exactly 3 cache lines).
// =====================================================================
#define SPP 524

__global__ __launch_bounds__(192) void sampler_kernel(
    const float* __restrict__ off_buf,    // (M, 256) fp32
    const float* __restrict__ logit_top,  // (M, 128)
    const float* __restrict__ logit_bot,  // (M, 128)
    const float* __restrict__ ref_pts,    // (M, 4, 2)
    const int*   __restrict__ ss,         // (4,2) [H,W]
    const int*   __restrict__ lsi,        // (4,)
    const __hip_bfloat16* __restrict__ vcomb,  // (Mv, 768) combined
    __hip_bfloat16* __restrict__ core_top,     // (M, 384) bf16
    __hip_bfloat16* __restrict__ core_bot,     // (M, 384) bf16
    int Lq, int LenIn)
{
    __shared__ float    sA[2][128];    // [br][e] softmaxed attn
    __shared__ unsigned sP[2][SPP];    // packed (bf16 w*attn)<<16 | point
    __shared__ float4   sRed[96][2];   // half-1 partial sums

    const int bid = blockIdx.x;        // query index
    const int t   = threadIdx.x;

    float gw[4];
    int   gp[4];

    // ---- phase 1: geometry for e = t (t < 128) ----
    if (t < 128) {
        const int e = t;
        const int n = bid / Lq;
        const int l = (e >> 2) & 3;
        const float2 offv = *(const float2*)&off_buf[(size_t)bid * 256 + 2 * e];
        const float rx = ref_pts[(size_t)(bid * 4 + l) * 2 + 0];
        const float ry = ref_pts[(size_t)(bid * 4 + l) * 2 + 1];
        const int H = ss[2 * l], W = ss[2 * l + 1];
        const int start = lsi[l];

        const float x = (rx + offv.x / (float)W) * (float)W - 0.5f;
        const float y = (ry + offv.y / (float)H) * (float)H - 0.5f;
        const float x0f = floorf(x), y0f = floorf(y);
        const float lx = x - x0f, ly = y - y0f;
        const int ix0 = (int)x0f, iy0 = (int)y0f;
        const int ix1 = ix0 + 1,  iy1 = iy0 + 1;

        const float vx0 = (ix0 >= 0 && ix0 < W) ? 1.f : 0.f;
        const float vx1 = (ix1 >= 0 && ix1 < W) ? 1.f : 0.f;
        const float vy0 = (iy0 >= 0 && iy0 < H) ? 1.f : 0.f;
        const float vy1 = (iy1 >= 0 && iy1 < H) ? 1.f : 0.f;
        const int cx0 = min(max(ix0, 0), W - 1);
        const int cx1 = min(max(ix1, 0), W - 1);
        const int cy0 = min(max(iy0, 0), H - 1);
        const int cy1 = min(max(iy1, 0), H - 1);
        const int base = bid / Lq * LenIn + start;
        (void)n;

        gp[0] = base + cy0 * W + cx0;
        gp[1] = base + cy0 * W + cx1;
        gp[2] = base + cy1 * W + cx0;
        gp[3] = base + cy1 * W + cx1;
        gw[0] = (1.f - lx) * (1.f - ly) * vx0 * vy0;
        gw[1] = lx * (1.f - ly) * vx1 * vy0;
        gw[2] = (1.f - lx) * ly * vx0 * vy1;
        gw[3] = lx * ly * vx1 * vy1;
    }

    // ---- softmax: t<16 -> (br = t>>3, h = t&7) ----
    if (t < 16) {
        const int br = t >> 3;
        const int h  = t & 7;
        const float* L = (br ? logit_bot : logit_top) + (size_t)bid * 128 + h * 16;
        float lg[16];
        *(float4*)&lg[0]  = *(const float4*)&L[0];
        *(float4*)&lg[4]  = *(const float4*)&L[4];
        *(float4*)&lg[8]  = *(const float4*)&L[8];
        *(float4*)&lg[12] = *(const float4*)&L[12];
        float m = -1e30f;
#pragma unroll
        for (int j = 0; j < 16; ++j) m = fmaxf(m, lg[j]);
        float ex[16], sum = 0.f;
#pragma unroll
        for (int j = 0; j < 16; ++j) { ex[j] = expf(lg[j] - m); sum += ex[j]; }
        const float inv = 1.f / sum;
#pragma unroll
        for (int j = 0; j < 16; ++j) sA[br][h * 16 + j] = ex[j] * inv;
    }
    __syncthreads();

    // ---- pack premultiplied weights + point indices ----
    if (t < 128) {
        const int e = t;
        const int pidx = 4 * e + (e >> 4);
#pragma unroll
        for (int br = 0; br < 2; ++br) {
            const float a = sA[br][e];
#pragma unroll
            for (int k = 0; k < 4; ++k) {
                sP[br][pidx + k] =
                    ((unsigned)f2bfbits(gw[k] * a) << 16) | (unsigned)gp[k];
            }
        }
    }
    __syncthreads();

    // ---- phase 3: gathers, split across two 96-thread halves ----
    const int half = t / 96;           // 0 or 1 -> lp range
    const int u    = t - half * 96;
    const int g    = u / 6;
    const int m    = u - g * 6;
    const int br   = g & 1;
    const int h    = g >> 1;

    const unsigned* P = sP[br];
    const char* vb = (const char*)vcomb + h * 192 + br * 96 + m * 16;

    float a0 = 0.f, a1 = 0.f, a2 = 0.f, a3 = 0.f;
    float a4 = 0.f, a5 = 0.f, a6 = 0.f, a7 = 0.f;
    const int lp0 = half * 8;
#pragma unroll
    for (int lp = 0; lp < 8; ++lp) {
        const int ib = 65 * h + 4 * (lp0 + lp);
#pragma unroll
        for (int k = 0; k < 4; ++k) {
            const unsigned uu = P[ib + k];
            const float wv = __uint_as_float(uu & 0xffff0000u);
            const unsigned pt = uu & 0x3fffu;
            const uint4 v = *(const uint4*)(vb + pt * 1536u);
            a0 = fmaf(wv, bflo(v.x), a0);
            a1 = fmaf(wv, bfhi(v.x), a1);
            a2 = fmaf(wv, bflo(v.y), a2);
            a3 = fmaf(wv, bfhi(v.y), a3);
            a4 = fmaf(wv, bflo(v.z), a4);
            a5 = fmaf(wv, bfhi(v.z), a5);
            a6 = fmaf(wv, bflo(v.w), a6);
            a7 = fmaf(wv, bfhi(v.w), a7);
        }
    }

    if (half) {
        float4 p0; p0.x = a0; p0.y = a1; p0.z = a2; p0.w = a3;
        float4 p1; p1.x = a4; p1.y = a5; p1.z = a6; p1.w = a7;
        sRed[u][0] = p0;
        sRed[u][1] = p1;
    }
    __syncthreads();
    if (!half) {
        const float4 p0 = sRed[u][0];
        const float4 p1 = sRed[u][1];
        uint4 o;
        o.x = pack2(a0 + p0.x, a1 + p0.y);
        o.y = pack2(a2 + p0.z, a3 + p0.w);
        o.z = pack2(a4 + p1.x, a5 + p1.y);
        o.w = pack2(a6 + p1.z, a7 + p1.w);
        __hip_bfloat16* dst = br ? core_bot : core_top;
        *(uint4*)&dst[(size_t)bid * DM + h * HD + m * 8] = o;
    }
}

// =====================================================================
// Host launcher — prep(weights) + GEMM1 + sampler + GEMM2.
// =====================================================================
extern "C" void kernel_launch(void* const* d_in, const int* in_sizes, int n_in,
                              void* d_out, int out_size, void* d_ws, size_t ws_size,
                              hipStream_t stream) {
    const float* query   = (const float*)d_in[0];
    const float* refpts  = (const float*)d_in[1];
    const float* flat    = (const float*)d_in[2];
    const int*   ss      = (const int*)d_in[3];
    const int*   lsi     = (const int*)d_in[4];
    const float* W_off   = (const float*)d_in[5];
    const float* b_off   = (const float*)d_in[6];
    const float* W_attn  = (const float*)d_in[7];
    const float* b_attn  = (const float*)d_in[8];
    const float* W_val   = (const float*)d_in[9];
    const float* b_val   = (const float*)d_in[10];
    const float* W_out   = (const float*)d_in[11];
    const float* b_out   = (const float*)d_in[12];
    const float* W_attn_zd = (const float*)d_in[13];
    const float* b_attn_zd = (const float*)d_in[14];
    const float* W_val_zd  = (const float*)d_in[15];
    const float* b_val_zd  = (const float*)d_in[16];
    const float* W_out_zd  = (const float*)d_in[17];
    const float* b_out_zd  = (const float*)d_in[18];

    const int Lq    = in_sizes[0] / (2 * DM);   // 5440
    const int LenIn = in_sizes[2] / (2 * DM);   // 5440
    const int M  = 2 * Lq;      // 10880
    const int Mv = 2 * LenIn;   // 10880

    float* out = (float*)d_out;

    // ---- workspace layout ----
    float* ws      = (float*)d_ws;
    float* off_buf = ws;                               // M*256 f32
    float* lt      = off_buf + (size_t)M * 256;        // M*128 f32
    float* lb      = lt + (size_t)M * 128;             // M*128 f32
    __hip_bfloat16* vcomb = (__hip_bfloat16*)(lb + (size_t)M * 128); // Mv*768
    __hip_bfloat16* ct    = vcomb + (size_t)Mv * 768;  // M*384
    __hip_bfloat16* cb    = ct + (size_t)M * 384;      // M*384
    __hip_bfloat16* wtb   = cb + (size_t)M * 384;      // transposed weights

    // ---- prep: weight transposes only ----
    PrepParams pp;
    const float* srcs[7] = {W_attn, W_attn_zd, W_val, W_val_zd, W_out, W_out_zd, W_off};
    const int Ks[7] = {256, 384, 256, 384, 384, 384, 256};
    const int Ns[7] = {128, 128, 384, 384, 256, 128, 256};
    __hip_bfloat16* dsts[7];
    int off = 0;
    for (int i = 0; i < 7; ++i) {
        pp.wsrc[i] = srcs[i]; pp.K[i] = Ks[i]; pp.N[i] = Ns[i];
        pp.off[i] = off;
        dsts[i] = wtb + off;
        pp.wdst[i] = dsts[i];
        off += Ks[i] * Ns[i];
    }
    pp.off[7] = off;
    pp.total = off;

    const dim3 blk(256);
    const int mg = M / 128;   // 85

    prep_kernel<<<dim3((pp.total + 255) / 256), blk, 0, stream>>>(pp);

    // ---- MEGA-GEMM 1: off + logits + values(combined scatter), grid (85,10)
    {
        SegParams p;
        p.seg[0] = { query, DM, 0, dsts[6], 256, b_off,     off_buf, 256, 256, 0 }; // y0-1
        p.seg[1] = { query, DM, 0, dsts[0], 256, b_attn,    lt,      128, 256, 0 }; // y2
        p.seg[2] = { query, DM, 0, dsts[1], 384, b_attn_zd, lb,      128, 384, 0 }; // y3
        p.seg[3] = { flat,  DM, 0, dsts[2], 256, b_val,     vcomb,   0,   256, 2 }; // y4-6
        p.seg[4] = { flat,  DM, 0, dsts[3], 384, b_val_zd,  vcomb,   0,   384, 3 }; // y7-9
        p.ystart[0] = 0; p.ystart[1] = 2; p.ystart[2] = 3;
        p.ystart[3] = 4; p.ystart[4] = 7;
        p.nseg = 5;
        gemm_seg_kernel<<<dim3(mg, 10), blk, 0, stream>>>(p);
    }

    // ---- sampler: 1 query per 192-thread block, split-point gathers ----
    sampler_kernel<<<dim3(M), dim3(192), 0, stream>>>(
        off_buf, lt, lb, refpts, ss, lsi, vcomb, ct, cb, Lq, LenIn);

    // ---- MEGA-GEMM 2: output projections, grid (85,3) ----
    {
        SegParams p;
        p.seg[0] = { ct, DM, 1, dsts[4], 384, b_out,    out,      DM, 384, 0 }; // y0-1
        p.seg[1] = { cb, DM, 1, dsts[5], 384, b_out_zd, out + U2, DM, 384, 0 }; // y2
        p.ystart[0] = 0; p.ystart[1] = 2;
        p.nseg = 2;
        gemm_seg_kernel<<<dim3(mg, 3), blk, 0, stream>>>(p);
    }
}

// Round 10
// 229.917 us; speedup vs baseline: 1.1175x; 1.1129x over previous
//
#include <hip/hip_runtime.h>
#include <hip/hip_bf16.h>
#include <math.h>

// Problem constants: N=2, D=384, 2U=256, nH=8, hd=48, nL=4, nP=4
#define DM   384
#define U2   256
#define HD   48

typedef __attribute__((ext_vector_type(8))) short short8;   // 8 bf16 = 4 VGPR
typedef __attribute__((ext_vector_type(4))) float floatx4;  // MFMA acc

static __device__ __forceinline__ unsigned short f2bfbits(float f) {
    __hip_bfloat16 h = __float2bfloat16(f);
    return *reinterpret_cast<unsigned short*>(&h);
}
static __device__ __forceinline__ unsigned pack2(float x, float y) {
    return (unsigned)f2bfbits(x) | ((unsigned)f2bfbits(y) << 16);
}
static __device__ __forceinline__ float bflo(unsigned u) { return __uint_as_float(u << 16); }
static __device__ __forceinline__ float bfhi(unsigned u) { return __uint_as_float(u & 0xffff0000u); }

// =====================================================================
// Prep: 7 weight transposes (K x N fp32 -> N x K bf16). Tiny (~475K elems).
// =====================================================================
struct PrepParams {
    const float* wsrc[7]; __hip_bfloat16* wdst[7];
    int K[7], N[7], off[8];
    int total;
};
__global__ __launch_bounds__(256) void prep_kernel(PrepParams d) {
    const int iw = blockIdx.x * 256 + threadIdx.x;
    if (iw >= d.total) return;
    int s = 0;
#pragma unroll
    for (int i = 1; i < 7; ++i) if (iw >= d.off[i]) s = i;
    const int r = iw - d.off[s];
    const int k = r / d.N[s], n = r - k * d.N[s];
    d.wdst[s][(size_t)n * d.K[s] + k] = __float2bfloat16(d.wsrc[s][r]);
}

// =====================================================================
// Multi-segment MFMA GEMM, 64x64 tile / BK=32 (latency-hiding config:
// 4x more blocks than 128-tile -> ~13 resident K-chains per CU).
//   - A: fp32 (aty=0, converted during LDS write) or bf16 (aty=1)
//   - B: pre-transposed bf16 (N x K), short8 loads
//   - LDS rows padded to 40 elems (2-way max = free)
//   - register prefetch: iter k+1 loads issue before iter k's MFMA
// omode: 0 = f32 out; 1 = bf16 out; 2/3 = bf16 scatter into combined
// value layout (top/bot): idx = row*768 + (col/48)*96 + (omode==3)*48 + col%48
// =====================================================================
struct Seg {
    const void* A; int lda; int aty;
    const __hip_bfloat16* Bt; int ldbt;
    const float* bias; void* C; int ldc; int K; int omode;
};
struct SegParams { Seg seg[5]; int ystart[5]; int nseg; };

__global__ __launch_bounds__(256) void gemm_seg_kernel(SegParams p) {
    __shared__ __hip_bfloat16 As[64 * 40];
    __shared__ __hip_bfloat16 Bs[64 * 40];

    const int yb = blockIdx.y;
    int s = 0;
#pragma unroll
    for (int i = 1; i < 5; ++i) if (i < p.nseg && yb >= p.ystart[i]) s = i;
    Seg sg;
    switch (s) {
        case 0: sg = p.seg[0]; break;
        case 1: sg = p.seg[1]; break;
        case 2: sg = p.seg[2]; break;
        case 3: sg = p.seg[3]; break;
        default: sg = p.seg[4]; break;
    }
    const int by = yb - p.ystart[s];

    const int t    = threadIdx.x;
    const int bm   = blockIdx.x * 64;
    const int bn   = by * 64;
    const int w    = t >> 6, lane = t & 63;
    const int wm   = (w >> 1) * 32, wn = (w & 1) * 32;
    const int quad = lane >> 4, lm = lane & 15;

    // staging map: thread -> row r0 (0..63), k-chunk kc (8 elems)
    const int r0 = t >> 2, kc = (t & 3) * 8;

    // prefetch registers
    float4 fa0, fa1;        // fp32 A path
    short8 abf;             // bf16 A path
    short8 bbf;             // B

    const bool atyb = (sg.aty != 0);

#define LOAD_REGS(K0)                                                          \
    do {                                                                       \
        if (atyb) {                                                            \
            abf = *(const short8*)((const __hip_bfloat16*)sg.A +               \
                (size_t)(bm + r0) * sg.lda + (K0) + kc);                       \
        } else {                                                               \
            const float* _src = (const float*)sg.A +                           \
                (size_t)(bm + r0) * sg.lda + (K0) + kc;                        \
            fa0 = *(const float4*)_src;                                        \
            fa1 = *(const float4*)(_src + 4);                                  \
        }                                                                      \
        bbf = *(const short8*)&sg.Bt[(size_t)(bn + r0) * sg.ldbt + (K0) + kc]; \
    } while (0)

    floatx4 acc[2][2] = {};

    LOAD_REGS(0);
    for (int k0 = 0; k0 < sg.K; k0 += 32) {
        // ---- write staged regs to LDS ----
        if (atyb) {
            *(short8*)&As[r0 * 40 + kc] = abf;
        } else {
            uint4 u;
            u.x = pack2(fa0.x, fa0.y); u.y = pack2(fa0.z, fa0.w);
            u.z = pack2(fa1.x, fa1.y); u.w = pack2(fa1.z, fa1.w);
            *(uint4*)&As[r0 * 40 + kc] = u;
        }
        *(short8*)&Bs[r0 * 40 + kc] = bbf;
        __syncthreads();

        // ---- prefetch next iteration (overlaps ds_read + MFMA) ----
        const int kn = k0 + 32;
        if (kn < sg.K) LOAD_REGS(kn);

        short8 af[2], bf[2];
#pragma unroll
        for (int i = 0; i < 2; ++i)
            af[i] = *(const short8*)&As[(wm + i * 16 + lm) * 40 + quad * 8];
#pragma unroll
        for (int j = 0; j < 2; ++j)
            bf[j] = *(const short8*)&Bs[(wn + j * 16 + lm) * 40 + quad * 8];
#pragma unroll
        for (int i = 0; i < 2; ++i)
#pragma unroll
            for (int j = 0; j < 2; ++j)
                acc[i][j] = __builtin_amdgcn_mfma_f32_16x16x32_bf16(
                    af[i], bf[j], acc[i][j], 0, 0, 0);
        __syncthreads();
    }
#undef LOAD_REGS

#pragma unroll
    for (int i = 0; i < 2; ++i)
#pragma unroll
        for (int reg = 0; reg < 4; ++reg) {
            const int row = bm + wm + i * 16 + quad * 4 + reg;
#pragma unroll
            for (int j = 0; j < 2; ++j) {
                const int col = bn + wn + j * 16 + lm;
                const float v = acc[i][j][reg] + sg.bias[col];
                if (sg.omode == 0) {
                    ((float*)sg.C)[(size_t)row * sg.ldc + col] = v;
                } else if (sg.omode == 1) {
                    ((__hip_bfloat16*)sg.C)[(size_t)row * sg.ldc + col] = __float2bfloat16(v);
                } else {
                    const int h = col / 48;
                    const size_t idx = (size_t)row * 768 + h * 96 +
                                       ((sg.omode == 3) ? 48 : 0) + (col - h * 48);
                    ((__hip_bfloat16*)sg.C)[idx] = __float2bfloat16(v);
                }
            }
        }
}

// =====================================================================
// Fused sampler v9 (kept): ONE query per 192-thread block; 16-point loop
// split across two 96-thread halves (32 loads/thread); partials via LDS.
// Phase 3 gather: (br,h) group of 6 threads; uint4 gathers from combined
// value layout (point row 1536B = [h][br][48ch]); 12 consecutive lanes
// read one contiguous 192B slab (exactly 3 cache lines).
// =====================================================================
#define SPP 524

__global__ __launch_bounds__(192) void sampler_kernel(
    const float* __restrict__ off_buf,    // (M, 256) fp32
    const float* __restrict__ logit_top,  // (M, 128)
    const float* __restrict__ logit_bot,  // (M, 128)
    const float* __restrict__ ref_pts,    // (M, 4, 2)
    const int*   __restrict__ ss,         // (4,2) [H,W]
    const int*   __restrict__ lsi,        // (4,)
    const __hip_bfloat16* __restrict__ vcomb,  // (Mv, 768) combined
    __hip_bfloat16* __restrict__ core_top,     // (M, 384) bf16
    __hip_bfloat16* __restrict__ core_bot,     // (M, 384) bf16
    int Lq, int LenIn)
{
    __shared__ float    sA[2][128];
    __shared__ unsigned sP[2][SPP];
    __shared__ float4   sRed[96][2];

    const int bid = blockIdx.x;
    const int t   = threadIdx.x;

    float gw[4];
    int   gp[4];

    if (t < 128) {
        const int e = t;
        const int l = (e >> 2) & 3;
        const float2 offv = *(const float2*)&off_buf[(size_t)bid * 256 + 2 * e];
        const float rx = ref_pts[(size_t)(bid * 4 + l) * 2 + 0];
        const float ry = ref_pts[(size_t)(bid * 4 + l) * 2 + 1];
        const int H = ss[2 * l], W = ss[2 * l + 1];
        const int start = lsi[l];

        const float x = (rx + offv.x / (float)W) * (float)W - 0.5f;
        const float y = (ry + offv.y / (float)H) * (float)H - 0.5f;
        const float x0f = floorf(x), y0f = floorf(y);
        const float lx = x - x0f, ly = y - y0f;
        const int ix0 = (int)x0f, iy0 = (int)y0f;
        const int ix1 = ix0 + 1,  iy1 = iy0 + 1;

        const float vx0 = (ix0 >= 0 && ix0 < W) ? 1.f : 0.f;
        const float vx1 = (ix1 >= 0 && ix1 < W) ? 1.f : 0.f;
        const float vy0 = (iy0 >= 0 && iy0 < H) ? 1.f : 0.f;
        const float vy1 = (iy1 >= 0 && iy1 < H) ? 1.f : 0.f;
        const int cx0 = min(max(ix0, 0), W - 1);
        const int cx1 = min(max(ix1, 0), W - 1);
        const int cy0 = min(max(iy0, 0), H - 1);
        const int cy1 = min(max(iy1, 0), H - 1);
        const int base = bid / Lq * LenIn + start;

        gp[0] = base + cy0 * W + cx0;
        gp[1] = base + cy0 * W + cx1;
        gp[2] = base + cy1 * W + cx0;
        gp[3] = base + cy1 * W + cx1;
        gw[0] = (1.f - lx) * (1.f - ly) * vx0 * vy0;
        gw[1] = lx * (1.f - ly) * vx1 * vy0;
        gw[2] = (1.f - lx) * ly * vx0 * vy1;
        gw[3] = lx * ly * vx1 * vy1;
    }

    if (t < 16) {
        const int br = t >> 3;
        const int h  = t & 7;
        const float* L = (br ? logit_bot : logit_top) + (size_t)bid * 128 + h * 16;
        float lg[16];
        *(float4*)&lg[0]  = *(const float4*)&L[0];
        *(float4*)&lg[4]  = *(const float4*)&L[4];
        *(float4*)&lg[8]  = *(const float4*)&L[8];
        *(float4*)&lg[12] = *(const float4*)&L[12];
        float m = -1e30f;
#pragma unroll
        for (int j = 0; j < 16; ++j) m = fmaxf(m, lg[j]);
        float ex[16], sum = 0.f;
#pragma unroll
        for (int j = 0; j < 16; ++j) { ex[j] = expf(lg[j] - m); sum += ex[j]; }
        const float inv = 1.f / sum;
#pragma unroll
        for (int j = 0; j < 16; ++j) sA[br][h * 16 + j] = ex[j] * inv;
    }
    __syncthreads();

    if (t < 128) {
        const int e = t;
        const int pidx = 4 * e + (e >> 4);
#pragma unroll
        for (int br = 0; br < 2; ++br) {
            const float a = sA[br][e];
#pragma unroll
            for (int k = 0; k < 4; ++k) {
                sP[br][pidx + k] =
                    ((unsigned)f2bfbits(gw[k] * a) << 16) | (unsigned)gp[k];
            }
        }
    }
    __syncthreads();

    const int half = t / 96;
    const int u    = t - half * 96;
    const int g    = u / 6;
    const int m    = u - g * 6;
    const int br   = g & 1;
    const int h    = g >> 1;

    const unsigned* P = sP[br];
    const char* vb = (const char*)vcomb + h * 192 + br * 96 + m * 16;

    float a0 = 0.f, a1 = 0.f, a2 = 0.f, a3 = 0.f;
    float a4 = 0.f, a5 = 0.f, a6 = 0.f, a7 = 0.f;
    const int lp0 = half * 8;
#pragma unroll
    for (int lp = 0; lp < 8; ++lp) {
        const int ib = 65 * h + 4 * (lp0 + lp);
#pragma unroll
        for (int k = 0; k < 4; ++k) {
            const unsigned uu = P[ib + k];
            const float wv = __uint_as_float(uu & 0xffff0000u);
            const unsigned pt = uu & 0x3fffu;
            const uint4 v = *(const uint4*)(vb + pt * 1536u);
            a0 = fmaf(wv, bflo(v.x), a0);
            a1 = fmaf(wv, bfhi(v.x), a1);
            a2 = fmaf(wv, bflo(v.y), a2);
            a3 = fmaf(wv, bfhi(v.y), a3);
            a4 = fmaf(wv, bflo(v.z), a4);
            a5 = fmaf(wv, bfhi(v.z), a5);
            a6 = fmaf(wv, bflo(v.w), a6);
            a7 = fmaf(wv, bfhi(v.w), a7);
        }
    }

    if (half) {
        float4 p0; p0.x = a0; p0.y = a1; p0.z = a2; p0.w = a3;
        float4 p1; p1.x = a4; p1.y = a5; p1.z = a6; p1.w = a7;
        sRed[u][0] = p0;
        sRed[u][1] = p1;
    }
    __syncthreads();
    if (!half) {
        const float4 p0 = sRed[u][0];
        const float4 p1 = sRed[u][1];
        uint4 o;
        o.x = pack2(a0 + p0.x, a1 + p0.y);
        o.y = pack2(a2 + p0.z, a3 + p0.w);
        o.z = pack2(a4 + p1.x, a5 + p1.y);
        o.w = pack2(a6 + p1.z, a7 + p1.w);
        __hip_bfloat16* dst = br ? core_bot : core_top;
        *(uint4*)&dst[(size_t)bid * DM + h * HD + m * 8] = o;
    }
}

// =====================================================================
// Host launcher — prep(weights) + GEMM1 + sampler + GEMM2.
// =====================================================================
extern "C" void kernel_launch(void* const* d_in, const int* in_sizes, int n_in,
                              void* d_out, int out_size, void* d_ws, size_t ws_size,
                              hipStream_t stream) {
    const float* query   = (const float*)d_in[0];
    const float* refpts  = (const float*)d_in[1];
    const float* flat    = (const float*)d_in[2];
    const int*   ss      = (const int*)d_in[3];
    const int*   lsi     = (const int*)d_in[4];
    const float* W_off   = (const float*)d_in[5];
    const float* b_off   = (const float*)d_in[6];
    const float* W_attn  = (const float*)d_in[7];
    const float* b_attn  = (const float*)d_in[8];
    const float* W_val   = (const float*)d_in[9];
    const float* b_val   = (const float*)d_in[10];
    const float* W_out   = (const float*)d_in[11];
    const float* b_out   = (const float*)d_in[12];
    const float* W_attn_zd = (const float*)d_in[13];
    const float* b_attn_zd = (const float*)d_in[14];
    const float* W_val_zd  = (const float*)d_in[15];
    const float* b_val_zd  = (const float*)d_in[16];
    const float* W_out_zd  = (const float*)d_in[17];
    const float* b_out_zd  = (const float*)d_in[18];

    const int Lq    = in_sizes[0] / (2 * DM);   // 5440
    const int LenIn = in_sizes[2] / (2 * DM);   // 5440
    const int M  = 2 * Lq;      // 10880
    const int Mv = 2 * LenIn;   // 10880

    float* out = (float*)d_out;

    // ---- workspace layout ----
    float* ws      = (float*)d_ws;
    float* off_buf = ws;                               // M*256 f32
    float* lt      = off_buf + (size_t)M * 256;        // M*128 f32
    float* lb      = lt + (size_t)M * 128;             // M*128 f32
    __hip_bfloat16* vcomb = (__hip_bfloat16*)(lb + (size_t)M * 128); // Mv*768
    __hip_bfloat16* ct    = vcomb + (size_t)Mv * 768;  // M*384
    __hip_bfloat16* cb    = ct + (size_t)M * 384;      // M*384
    __hip_bfloat16* wtb   = cb + (size_t)M * 384;      // transposed weights

    // ---- prep: weight transposes only ----
    PrepParams pp;
    const float* srcs[7] = {W_attn, W_attn_zd, W_val, W_val_zd, W_out, W_out_zd, W_off};
    const int Ks[7] = {256, 384, 256, 384, 384, 384, 256};
    const int Ns[7] = {128, 128, 384, 384, 256, 128, 256};
    __hip_bfloat16* dsts[7];
    int off = 0;
    for (int i = 0; i < 7; ++i) {
        pp.wsrc[i] = srcs[i]; pp.K[i] = Ks[i]; pp.N[i] = Ns[i];
        pp.off[i] = off;
        dsts[i] = wtb + off;
        pp.wdst[i] = dsts[i];
        off += Ks[i] * Ns[i];
    }
    pp.off[7] = off;
    pp.total = off;

    const dim3 blk(256);
    const int mg = M / 64;   // 170

    prep_kernel<<<dim3((pp.total + 255) / 256), blk, 0, stream>>>(pp);

    // ---- MEGA-GEMM 1: off + logits + values(combined scatter), grid (170,20)
    {
        SegParams p;
        p.seg[0] = { query, DM, 0, dsts[6], 256, b_off,     off_buf, 256, 256, 0 }; // y0-3
        p.seg[1] = { query, DM, 0, dsts[0], 256, b_attn,    lt,      128, 256, 0 }; // y4-5
        p.seg[2] = { query, DM, 0, dsts[1], 384, b_attn_zd, lb,      128, 384, 0 }; // y6-7
        p.seg[3] = { flat,  DM, 0, dsts[2], 256, b_val,     vcomb,   0,   256, 2 }; // y8-13
        p.seg[4] = { flat,  DM, 0, dsts[3], 384, b_val_zd,  vcomb,   0,   384, 3 }; // y14-19
        p.ystart[0] = 0; p.ystart[1] = 4; p.ystart[2] = 6;
        p.ystart[3] = 8; p.ystart[4] = 14;
        p.nseg = 5;
        gemm_seg_kernel<<<dim3(mg, 20), blk, 0, stream>>>(p);
    }

    // ---- sampler: 1 query per 192-thread block, split-point gathers ----
    sampler_kernel<<<dim3(M), dim3(192), 0, stream>>>(
        off_buf, lt, lb, refpts, ss, lsi, vcomb, ct, cb, Lq, LenIn);

    // ---- MEGA-GEMM 2: output projections, grid (170,6) ----
    {
        SegParams p;
        p.seg[0] = { ct, DM, 1, dsts[4], 384, b_out,    out,      DM, 384, 0 }; // y0-3
        p.seg[1] = { cb, DM, 1, dsts[5], 384, b_out_zd, out + U2, DM, 384, 0 }; // y4-5
        p.ystart[0] = 0; p.ystart[1] = 4;
        p.nseg = 2;
        gemm_seg_kernel<<<dim3(mg, 6), blk, 0, stream>>>(p);
    }
}

// Round 11
// 220.309 us; speedup vs baseline: 1.1663x; 1.0436x over previous
//
#include <hip/hip_runtime.h>
#include <hip/hip_bf16.h>
#include <math.h>

// Problem constants: N=2, D=384, 2U=256, nH=8, hd=48, nL=4, nP=4
#define DM   384
#define U2   256
#define HD   48

typedef __attribute__((ext_vector_type(8))) short short8;   // 8 bf16 = 4 VGPR
typedef __attribute__((ext_vector_type(4))) float floatx4;  // MFMA acc
typedef __attribute__((ext_vector_type(2))) float floatx2;  // pk_fma pair

static __device__ __forceinline__ unsigned short f2bfbits(float f) {
    __hip_bfloat16 h = __float2bfloat16(f);
    return *reinterpret_cast<unsigned short*>(&h);
}
static __device__ __forceinline__ unsigned pack2(float x, float y) {
    return (unsigned)f2bfbits(x) | ((unsigned)f2bfbits(y) << 16);
}
static __device__ __forceinline__ float bflo(unsigned u) { return __uint_as_float(u << 16); }
static __device__ __forceinline__ float bfhi(unsigned u) { return __uint_as_float(u & 0xffff0000u); }

// =====================================================================
// Prep: query->bf16, flat->bf16 (vectorized) + 7 weight transposes.
// =====================================================================
struct PrepParams {
    const float* q; const float* f;
    __hip_bfloat16 *q_bf, *f_bf;
    const float* wsrc[7]; __hip_bfloat16* wdst[7];
    int K[7], N[7], off[8];
    int nQ4, nF4, total;
};
__global__ __launch_bounds__(256) void prep_kernel(PrepParams d) {
    const int idx = blockIdx.x * 256 + threadIdx.x;
    if (idx >= d.total) return;
    if (idx < d.nQ4) {
        const int i4 = idx * 4;
        const float4 v = *(const float4*)&d.q[i4];
        uint2 pk; pk.x = pack2(v.x, v.y); pk.y = pack2(v.z, v.w);
        *(uint2*)&d.q_bf[i4] = pk;
        return;
    }
    if (idx < d.nQ4 + d.nF4) {
        const int i4 = (idx - d.nQ4) * 4;
        const float4 v = *(const float4*)&d.f[i4];
        uint2 pk; pk.x = pack2(v.x, v.y); pk.y = pack2(v.z, v.w);
        *(uint2*)&d.f_bf[i4] = pk;
        return;
    }
    const int iw = idx - d.nQ4 - d.nF4;
    int s = 0;
#pragma unroll
    for (int i = 1; i < 7; ++i) if (iw >= d.off[i]) s = i;
    const int r = iw - d.off[s];
    const int k = r / d.N[s], n = r - k * d.N[s];
    d.wdst[s][(size_t)n * d.K[s] + k] = __float2bfloat16(d.wsrc[s][r]);
}

// =====================================================================
// Multi-segment MFMA GEMM, 64x64 tile / BK=32 (R10-proven latency-hiding
// config, now with bf16 A everywhere: halves the redundant A traffic
// that 64-wide y-blocks re-read).
// omode: 0 = f32 out; 1 = bf16 out; 2/3 = bf16 scatter into combined
// value layout (top/bot): idx = row*768 + (col/48)*96 + (omode==3)*48 + col%48
// =====================================================================
struct Seg {
    const __hip_bfloat16* A; int lda;
    const __hip_bfloat16* Bt; int ldbt;
    const float* bias; void* C; int ldc; int K; int omode;
};
struct SegParams { Seg seg[5]; int ystart[5]; int nseg; };

__global__ __launch_bounds__(256) void gemm_seg_kernel(SegParams p) {
    __shared__ __hip_bfloat16 As[64 * 40];
    __shared__ __hip_bfloat16 Bs[64 * 40];

    const int yb = blockIdx.y;
    int s = 0;
#pragma unroll
    for (int i = 1; i < 5; ++i) if (i < p.nseg && yb >= p.ystart[i]) s = i;
    Seg sg;
    switch (s) {
        case 0: sg = p.seg[0]; break;
        case 1: sg = p.seg[1]; break;
        case 2: sg = p.seg[2]; break;
        case 3: sg = p.seg[3]; break;
        default: sg = p.seg[4]; break;
    }
    const int by = yb - p.ystart[s];

    const int t    = threadIdx.x;
    const int bm   = blockIdx.x * 64;
    const int bn   = by * 64;
    const int w    = t >> 6, lane = t & 63;
    const int wm   = (w >> 1) * 32, wn = (w & 1) * 32;
    const int quad = lane >> 4, lm = lane & 15;

    const int r0 = t >> 2, kc = (t & 3) * 8;

    const __hip_bfloat16* Ap = sg.A  + (size_t)(bm + r0) * sg.lda  + kc;
    const __hip_bfloat16* Bp = sg.Bt + (size_t)(bn + r0) * sg.ldbt + kc;

    short8 abf = *(const short8*)Ap;
    short8 bbf = *(const short8*)Bp;

    floatx4 acc[2][2] = {};

    for (int k0 = 0; k0 < sg.K; k0 += 32) {
        *(short8*)&As[r0 * 40 + kc] = abf;
        *(short8*)&Bs[r0 * 40 + kc] = bbf;
        __syncthreads();

        const int kn = k0 + 32;
        if (kn < sg.K) {
            abf = *(const short8*)(Ap + kn);
            bbf = *(const short8*)(Bp + kn);
        }

        short8 af[2], bf[2];
#pragma unroll
        for (int i = 0; i < 2; ++i)
            af[i] = *(const short8*)&As[(wm + i * 16 + lm) * 40 + quad * 8];
#pragma unroll
        for (int j = 0; j < 2; ++j)
            bf[j] = *(const short8*)&Bs[(wn + j * 16 + lm) * 40 + quad * 8];
#pragma unroll
        for (int i = 0; i < 2; ++i)
#pragma unroll
            for (int j = 0; j < 2; ++j)
                acc[i][j] = __builtin_amdgcn_mfma_f32_16x16x32_bf16(
                    af[i], bf[j], acc[i][j], 0, 0, 0);
        __syncthreads();
    }

#pragma unroll
    for (int i = 0; i < 2; ++i)
#pragma unroll
        for (int reg = 0; reg < 4; ++reg) {
            const int row = bm + wm + i * 16 + quad * 4 + reg;
#pragma unroll
            for (int j = 0; j < 2; ++j) {
                const int col = bn + wn + j * 16 + lm;
                const float v = acc[i][j][reg] + sg.bias[col];
                if (sg.omode == 0) {
                    ((float*)sg.C)[(size_t)row * sg.ldc + col] = v;
                } else if (sg.omode == 1) {
                    ((__hip_bfloat16*)sg.C)[(size_t)row * sg.ldc + col] = __float2bfloat16(v);
                } else {
                    const int h = col / 48;
                    const size_t idx = (size_t)row * 768 + h * 96 +
                                       ((sg.omode == 3) ? 48 : 0) + (col - h * 48);
                    ((__hip_bfloat16*)sg.C)[idx] = __float2bfloat16(v);
                }
            }
        }
}

// =====================================================================
// Fused sampler v11: v9 structure (1 query / 192 thr, split halves) with
// a VALU diet in phase 3:
//   - SGPR-base + 32-bit voffset addressing: off = mad24(pt, 1536, tco)
//   - float2 accumulators -> v_pk_fma_f32 (8 fma -> 4 pk_fma per load)
// =====================================================================
#define SPP 524

__global__ __launch_bounds__(192) void sampler_kernel(
    const float* __restrict__ off_buf,    // (M, 256) fp32
    const float* __restrict__ logit_top,  // (M, 128)
    const float* __restrict__ logit_bot,  // (M, 128)
    const float* __restrict__ ref_pts,    // (M, 4, 2)
    const int*   __restrict__ ss,         // (4,2) [H,W]
    const int*   __restrict__ lsi,        // (4,)
    const __hip_bfloat16* __restrict__ vcomb,  // (Mv, 768) combined
    __hip_bfloat16* __restrict__ core_top,     // (M, 384) bf16
    __hip_bfloat16* __restrict__ core_bot,     // (M, 384) bf16
    int Lq, int LenIn)
{
    __shared__ float    sA[2][128];
    __shared__ unsigned sP[2][SPP];
    __shared__ float4   sRed[96][2];

    const int bid = blockIdx.x;
    const int t   = threadIdx.x;

    float gw[4];
    int   gp[4];

    if (t < 128) {
        const int e = t;
        const int l = (e >> 2) & 3;
        const float2 offv = *(const float2*)&off_buf[(size_t)bid * 256 + 2 * e];
        const float rx = ref_pts[(size_t)(bid * 4 + l) * 2 + 0];
        const float ry = ref_pts[(size_t)(bid * 4 + l) * 2 + 1];
        const int H = ss[2 * l], W = ss[2 * l + 1];
        const int start = lsi[l];

        const float x = (rx + offv.x / (float)W) * (float)W - 0.5f;
        const float y = (ry + offv.y / (float)H) * (float)H - 0.5f;
        const float x0f = floorf(x), y0f = floorf(y);
        const float lx = x - x0f, ly = y - y0f;
        const int ix0 = (int)x0f, iy0 = (int)y0f;
        const int ix1 = ix0 + 1,  iy1 = iy0 + 1;

        const float vx0 = (ix0 >= 0 && ix0 < W) ? 1.f : 0.f;
        const float vx1 = (ix1 >= 0 && ix1 < W) ? 1.f : 0.f;
        const float vy0 = (iy0 >= 0 && iy0 < H) ? 1.f : 0.f;
        const float vy1 = (iy1 >= 0 && iy1 < H) ? 1.f : 0.f;
        const int cx0 = min(max(ix0, 0), W - 1);
        const int cx1 = min(max(ix1, 0), W - 1);
        const int cy0 = min(max(iy0, 0), H - 1);
        const int cy1 = min(max(iy1, 0), H - 1);
        const int base = bid / Lq * LenIn + start;

        gp[0] = base + cy0 * W + cx0;
        gp[1] = base + cy0 * W + cx1;
        gp[2] = base + cy1 * W + cx0;
        gp[3] = base + cy1 * W + cx1;
        gw[0] = (1.f - lx) * (1.f - ly) * vx0 * vy0;
        gw[1] = lx * (1.f - ly) * vx1 * vy0;
        gw[2] = (1.f - lx) * ly * vx0 * vy1;
        gw[3] = lx * ly * vx1 * vy1;
    }

    if (t < 16) {
        const int br = t >> 3;
        const int h  = t & 7;
        const float* L = (br ? logit_bot : logit_top) + (size_t)bid * 128 + h * 16;
        float lg[16];
        *(float4*)&lg[0]  = *(const float4*)&L[0];
        *(float4*)&lg[4]  = *(const float4*)&L[4];
        *(float4*)&lg[8]  = *(const float4*)&L[8];
        *(float4*)&lg[12] = *(const float4*)&L[12];
        float m = -1e30f;
#pragma unroll
        for (int j = 0; j < 16; ++j) m = fmaxf(m, lg[j]);
        float ex[16], sum = 0.f;
#pragma unroll
        for (int j = 0; j < 16; ++j) { ex[j] = expf(lg[j] - m); sum += ex[j]; }
        const float inv = 1.f / sum;
#pragma unroll
        for (int j = 0; j < 16; ++j) sA[br][h * 16 + j] = ex[j] * inv;
    }
    __syncthreads();

    if (t < 128) {
        const int e = t;
        const int pidx = 4 * e + (e >> 4);
#pragma unroll
        for (int br = 0; br < 2; ++br) {
            const float a = sA[br][e];
#pragma unroll
            for (int k = 0; k < 4; ++k) {
                sP[br][pidx + k] =
                    ((unsigned)f2bfbits(gw[k] * a) << 16) | (unsigned)gp[k];
            }
        }
    }
    __syncthreads();

    // ---- phase 3: gathers ----
    const int half = t / 96;
    const int u    = t - half * 96;
    const int g    = u / 6;
    const int m    = u - g * 6;
    const int br   = g & 1;
    const int h    = g >> 1;

    const unsigned* P = sP[br];
    const char* vbase = (const char*)vcomb;             // uniform SGPR base
    const unsigned tco = (unsigned)(h * 192 + br * 96 + m * 16);

    floatx2 ac0 = {0.f, 0.f}, ac1 = {0.f, 0.f};
    floatx2 ac2 = {0.f, 0.f}, ac3 = {0.f, 0.f};
    const int lp0 = half * 8;
#pragma unroll
    for (int lp = 0; lp < 8; ++lp) {
        const int ib = 65 * h + 4 * (lp0 + lp);
#pragma unroll
        for (int k = 0; k < 4; ++k) {
            const unsigned uu = P[ib + k];
            const float wv = __uint_as_float(uu & 0xffff0000u);
            const unsigned off = (uu & 0x3fffu) * 1536u + tco;  // mad24-able
            const uint4 v = *(const uint4*)(vbase + off);
            floatx2 wv2 = {wv, wv};
            floatx2 f0 = {bflo(v.x), bfhi(v.x)};
            floatx2 f1 = {bflo(v.y), bfhi(v.y)};
            floatx2 f2 = {bflo(v.z), bfhi(v.z)};
            floatx2 f3 = {bflo(v.w), bfhi(v.w)};
            ac0 += wv2 * f0;
            ac1 += wv2 * f1;
            ac2 += wv2 * f2;
            ac3 += wv2 * f3;
        }
    }

    if (half) {
        float4 p0; p0.x = ac0.x; p0.y = ac0.y; p0.z = ac1.x; p0.w = ac1.y;
        float4 p1; p1.x = ac2.x; p1.y = ac2.y; p1.z = ac3.x; p1.w = ac3.y;
        sRed[u][0] = p0;
        sRed[u][1] = p1;
    }
    __syncthreads();
    if (!half) {
        const float4 p0 = sRed[u][0];
        const float4 p1 = sRed[u][1];
        uint4 o;
        o.x = pack2(ac0.x + p0.x, ac0.y + p0.y);
        o.y = pack2(ac1.x + p0.z, ac1.y + p0.w);
        o.z = pack2(ac2.x + p1.x, ac2.y + p1.y);
        o.w = pack2(ac3.x + p1.z, ac3.y + p1.w);
        __hip_bfloat16* dst = br ? core_bot : core_top;
        *(uint4*)&dst[(size_t)bid * DM + h * HD + m * 8] = o;
    }
}

// =====================================================================
// Host launcher — prep(q/f/weights) + GEMM1 + sampler + GEMM2.
// =====================================================================
extern "C" void kernel_launch(void* const* d_in, const int* in_sizes, int n_in,
                              void* d_out, int out_size, void* d_ws, size_t ws_size,
                              hipStream_t stream) {
    const float* query   = (const float*)d_in[0];
    const float* refpts  = (const float*)d_in[1];
    const float* flat    = (const float*)d_in[2];
    const int*   ss      = (const int*)d_in[3];
    const int*   lsi     = (const int*)d_in[4];
    const float* W_off   = (const float*)d_in[5];
    const float* b_off   = (const float*)d_in[6];
    const float* W_attn  = (const float*)d_in[7];
    const float* b_attn  = (const float*)d_in[8];
    const float* W_val   = (const float*)d_in[9];
    const float* b_val   = (const float*)d_in[10];
    const float* W_out   = (const float*)d_in[11];
    const float* b_out   = (const float*)d_in[12];
    const float* W_attn_zd = (const float*)d_in[13];
    const float* b_attn_zd = (const float*)d_in[14];
    const float* W_val_zd  = (const float*)d_in[15];
    const float* b_val_zd  = (const float*)d_in[16];
    const float* W_out_zd  = (const float*)d_in[17];
    const float* b_out_zd  = (const float*)d_in[18];

    const int Lq    = in_sizes[0] / (2 * DM);   // 5440
    const int LenIn = in_sizes[2] / (2 * DM);   // 5440
    const int M  = 2 * Lq;      // 10880
    const int Mv = 2 * LenIn;   // 10880

    float* out = (float*)d_out;

    // ---- workspace layout ----
    float* ws      = (float*)d_ws;
    float* off_buf = ws;                               // M*256 f32
    float* lt      = off_buf + (size_t)M * 256;        // M*128 f32
    float* lb      = lt + (size_t)M * 128;             // M*128 f32
    __hip_bfloat16* q_bf  = (__hip_bfloat16*)(lb + (size_t)M * 128); // M*384
    __hip_bfloat16* f_bf  = q_bf + (size_t)M * 384;    // Mv*384
    __hip_bfloat16* vcomb = f_bf + (size_t)Mv * 384;   // Mv*768 combined
    __hip_bfloat16* ct    = vcomb + (size_t)Mv * 768;  // M*384
    __hip_bfloat16* cb    = ct + (size_t)M * 384;      // M*384
    __hip_bfloat16* wtb   = cb + (size_t)M * 384;      // transposed weights

    // ---- prep: activations + weight transposes ----
    PrepParams pp;
    pp.q = query; pp.f = flat;
    pp.q_bf = q_bf; pp.f_bf = f_bf;
    const float* srcs[7] = {W_attn, W_attn_zd, W_val, W_val_zd, W_out, W_out_zd, W_off};
    const int Ks[7] = {256, 384, 256, 384, 384, 384, 256};
    const int Ns[7] = {128, 128, 384, 384, 256, 128, 256};
    __hip_bfloat16* dsts[7];
    int off = 0;
    for (int i = 0; i < 7; ++i) {
        pp.wsrc[i] = srcs[i]; pp.K[i] = Ks[i]; pp.N[i] = Ns[i];
        pp.off[i] = off;
        dsts[i] = wtb + off;
        pp.wdst[i] = dsts[i];
        off += Ks[i] * Ns[i];
    }
    pp.off[7] = off;
    pp.nQ4 = M * DM / 4;
    pp.nF4 = Mv * DM / 4;
    pp.total = pp.nQ4 + pp.nF4 + off;

    const dim3 blk(256);
    const int mg = M / 64;   // 170

    prep_kernel<<<dim3((pp.total + 255) / 256), blk, 0, stream>>>(pp);

    // ---- MEGA-GEMM 1: off + logits + values(combined scatter), grid (170,20)
    {
        SegParams p;
        p.seg[0] = { q_bf, DM, dsts[6], 256, b_off,     off_buf, 256, 256, 0 }; // y0-3
        p.seg[1] = { q_bf, DM, dsts[0], 256, b_attn,    lt,      128, 256, 0 }; // y4-5
        p.seg[2] = { q_bf, DM, dsts[1], 384, b_attn_zd, lb,      128, 384, 0 }; // y6-7
        p.seg[3] = { f_bf, DM, dsts[2], 256, b_val,     vcomb,   0,   256, 2 }; // y8-13
        p.seg[4] = { f_bf, DM, dsts[3], 384, b_val_zd,  vcomb,   0,   384, 3 }; // y14-19
        p.ystart[0] = 0; p.ystart[1] = 4; p.ystart[2] = 6;
        p.ystart[3] = 8; p.ystart[4] = 14;
        p.nseg = 5;
        gemm_seg_kernel<<<dim3(mg, 20), blk, 0, stream>>>(p);
    }

    // ---- sampler: 1 query per 192-thread block, split-point gathers ----
    sampler_kernel<<<dim3(M), dim3(192), 0, stream>>>(
        off_buf, lt, lb, refpts, ss, lsi, vcomb, ct, cb, Lq, LenIn);

    // ---- MEGA-GEMM 2: output projections, grid (170,6) ----
    {
        SegParams p;
        p.seg[0] = { ct, DM, dsts[4], 384, b_out,    out,      DM, 384, 0 }; // y0-3
        p.seg[1] = { cb, DM, dsts[5], 384, b_out_zd, out + U2, DM, 384, 0 }; // y4-5
        p.ystart[0] = 0; p.ystart[1] = 4;
        p.nseg = 2;
        gemm_seg_kernel<<<dim3(mg, 6), blk, 0, stream>>>(p);
    }
}